// Round 6
// baseline (434.470 us; speedup 1.0000x reference)
//
#include <hip/hip_runtime.h>
#include <stdint.h>

#define V 200000
#define E 600000
#define NB1 782          // ceil(V/256)

using bf16x8_t = __attribute__((ext_vector_type(8))) short;
using f32x4_t  = __attribute__((ext_vector_type(4))) float;

__device__ __forceinline__ unsigned short f2bf(float f) {
  unsigned int u = __float_as_uint(f);
  return (unsigned short)((u + 0x7fffu + ((u >> 16) & 1u)) >> 16);   // RNE
}
__device__ __forceinline__ float bf_lo(unsigned d) { return __uint_as_float(d << 16); }
__device__ __forceinline__ float bf_hi(unsigned d) { return __uint_as_float(d & 0xffff0000u); }
__device__ __forceinline__ float bf2f(unsigned short s) {
  return __uint_as_float(((unsigned)s) << 16);
}
__device__ __forceinline__ bf16x8_t pack8(const float4& q0, const float4& q1) {
  union { unsigned short us[8]; bf16x8_t v; } p;
  p.us[0]=f2bf(q0.x); p.us[1]=f2bf(q0.y); p.us[2]=f2bf(q0.z); p.us[3]=f2bf(q0.w);
  p.us[4]=f2bf(q1.x); p.us[5]=f2bf(q1.y); p.us[6]=f2bf(q1.z); p.us[7]=f2bf(q1.w);
  return p.v;
}

// ---------------------------------------------------------------------------
// prep_w2: fragment-linear weights; B operand = coalesced 1KB loads from L1/L2.
//   o = ((kg*24 + cg)*64 + lane)*8 + e ;  W[c][k], c=cg*16+(lane&15),
//   k = kg*32+(lane>>4)*8+e.  c<256 -> w0 ; c>=256 -> w1.
// ---------------------------------------------------------------------------
__global__ void prep_w2(const float* __restrict__ w0, const float* __restrict__ w1,
                        unsigned short* __restrict__ Wb2) {
  int o = blockIdx.x * 256 + threadIdx.x;        // 0..98303
  int kg = o / 12288;
  int r  = o - kg * 12288;
  int cg = r >> 9;
  int r2 = r & 511;
  int lane = r2 >> 3, e = r2 & 7;
  int c = cg * 16 + (lane & 15);
  int k = kg * 32 + (lane >> 4) * 8 + e;
  float v = (c < 256) ? w0[c * 256 + k] : w1[(c - 256) * 256 + k];
  Wb2[o] = f2bf(v);
}

// ---------------------------------------------------------------------------
// Pass 1: w1b[V,128] = bf16(verts @ w1^T + b1).
// Register-stationary: wave owns 16 rows x 128 cols; A frags built in regs
// from global (2 half-bursts), B direct from Wb2. No LDS, no barriers.
// ---------------------------------------------------------------------------
__global__ __launch_bounds__(256, 4) void gemm_w1(
    const float* __restrict__ verts, const unsigned short* __restrict__ Wb2,
    const float* __restrict__ w1_b, unsigned short* __restrict__ w1b)
{
  const int tid = threadIdx.x, lane = tid & 63, wv = tid >> 6;
  const int rBase = blockIdx.x * 64 + wv * 16;
  const float* vp = verts + (size_t)(rBase + (lane & 15)) * 256 + (lane >> 4) * 8;

  float4 q[8];
  #pragma unroll
  for (int kg = 0; kg < 4; ++kg) {
    q[2*kg]   = *(const float4*)(vp + kg * 32);
    q[2*kg+1] = *(const float4*)(vp + kg * 32 + 4);
  }

  f32x4_t acc[8];
  #pragma unroll
  for (int n = 0; n < 8; ++n) acc[n] = (f32x4_t){0.f,0.f,0.f,0.f};

  bf16x8_t af[4];
  #pragma unroll
  for (int kg = 0; kg < 4; ++kg) af[kg] = pack8(q[2*kg], q[2*kg+1]);
  #pragma unroll
  for (int kg = 0; kg < 4; ++kg) {                 // second half burst
    q[2*kg]   = *(const float4*)(vp + 128 + kg * 32);
    q[2*kg+1] = *(const float4*)(vp + 128 + kg * 32 + 4);
  }
  #pragma unroll
  for (int kg = 0; kg < 4; ++kg)
    #pragma unroll
    for (int n = 0; n < 8; ++n) {
      bf16x8_t b = *(const bf16x8_t*)(Wb2 + (size_t)(kg*24 + 16 + n) * 512 + lane * 8);
      acc[n] = __builtin_amdgcn_mfma_f32_16x16x32_bf16(af[kg], b, acc[n], 0,0,0);
    }
  #pragma unroll
  for (int kg = 0; kg < 4; ++kg) af[kg] = pack8(q[2*kg], q[2*kg+1]);
  #pragma unroll
  for (int kg = 4; kg < 8; ++kg)
    #pragma unroll
    for (int n = 0; n < 8; ++n) {
      bf16x8_t b = *(const bf16x8_t*)(Wb2 + (size_t)(kg*24 + 16 + n) * 512 + lane * 8);
      acc[n] = __builtin_amdgcn_mfma_f32_16x16x32_bf16(af[kg-4], b, acc[n], 0,0,0);
    }

  const int l15 = lane & 15, lq = lane >> 4;
  #pragma unroll
  for (int n = 0; n < 8; ++n) {
    int col = n * 16 + l15;
    float bias = w1_b[col];
    #pragma unroll
    for (int r = 0; r < 4; ++r)
      w1b[(size_t)(rBase + lq * 4 + r) * 128 + col] = f2bf(acc[n][r] + bias);
  }
}

// ---------------------------------------------------------------------------
// Pass 2: out[V,256] = verts @ w0^T + b0 + pad(segment_sum(w1b[adj])).
// Register-stationary, ZERO barriers. Wave owns 16 rows x 256 cols.
// Order: issue A half-burst; pipelined gather (8 loads deep, next-row index
// prefetch, masked accumulate; adj padded) -> per-wave nb slab in LDS;
// convert A / issue half 2; 128 MFMA; epilogue adds nb + single out write.
// ---------------------------------------------------------------------------
__global__ __launch_bounds__(256, 4) void gemm_w0_gather(
    const float* __restrict__ verts, const unsigned short* __restrict__ Wb2,
    const float* __restrict__ w0_b, const int* __restrict__ rowptr,
    const int* __restrict__ adj, const unsigned short* __restrict__ w1b,
    float* __restrict__ out)
{
  __shared__ unsigned nbu[4 * 16 * 65];            // 16.6 KB, wave-local use

  const int tid = threadIdx.x, lane = tid & 63, wv = tid >> 6;
  const int rBase = blockIdx.x * 64 + wv * 16;
  const float* vp = verts + (size_t)(rBase + (lane & 15)) * 256 + (lane >> 4) * 8;

  // A half-burst 1 — in flight through the gather
  float4 q[8];
  #pragma unroll
  for (int kg = 0; kg < 4; ++kg) {
    q[2*kg]   = *(const float4*)(vp + kg * 32);
    q[2*kg+1] = *(const float4*)(vp + kg * 32 + 4);
  }

  // ---- pipelined gather: rows rBase..rBase+16 ----
  {
    const unsigned* w1d = (const unsigned*)w1b;    // 64 dwords per row
    int s = rowptr[rBase];
    int uc[8];
    #pragma unroll
    for (int t = 0; t < 8; ++t) uc[t] = adj[s + t];          // padded at 2E
    #pragma unroll 1
    for (int rr = 0; rr < 16; ++rr) {
      int e = rowptr[rBase + rr + 1];
      unsigned d[8];
      #pragma unroll
      for (int t = 0; t < 8; ++t) d[t] = w1d[(size_t)uc[t] * 64 + lane];
      int un[8];
      #pragma unroll
      for (int t = 0; t < 8; ++t) un[t] = adj[e + t];        // next-row prefetch
      float g0 = 0.f, g1 = 0.f;
      #pragma unroll
      for (int t = 0; t < 8; ++t) {
        float x0 = (s + t < e) ? bf_lo(d[t]) : 0.f;
        float x1 = (s + t < e) ? bf_hi(d[t]) : 0.f;
        g0 += x0; g1 += x1;
      }
      for (int j = s + 8; j < e; j += 8) {                   // rare deg>8 tail
        int uo[8];
        #pragma unroll
        for (int t = 0; t < 8; ++t) uo[t] = adj[j + t];
        unsigned d2[8];
        #pragma unroll
        for (int t = 0; t < 8; ++t) d2[t] = w1d[(size_t)uo[t] * 64 + lane];
        #pragma unroll
        for (int t = 0; t < 8; ++t) {
          float x0 = (j + t < e) ? bf_lo(d2[t]) : 0.f;
          float x1 = (j + t < e) ? bf_hi(d2[t]) : 0.f;
          g0 += x0; g1 += x1;
        }
      }
      nbu[(wv * 16 + rr) * 65 + lane] =
          (unsigned)f2bf(g0) | ((unsigned)f2bf(g1) << 16);   // cols {2l, 2l+1}
      s = e;
      #pragma unroll
      for (int t = 0; t < 8; ++t) uc[t] = un[t];
    }
  }

  f32x4_t acc[16];
  #pragma unroll
  for (int n = 0; n < 16; ++n) acc[n] = (f32x4_t){0.f,0.f,0.f,0.f};

  bf16x8_t af[4];
  #pragma unroll
  for (int kg = 0; kg < 4; ++kg) af[kg] = pack8(q[2*kg], q[2*kg+1]);
  #pragma unroll
  for (int kg = 0; kg < 4; ++kg) {                 // A half-burst 2
    q[2*kg]   = *(const float4*)(vp + 128 + kg * 32);
    q[2*kg+1] = *(const float4*)(vp + 128 + kg * 32 + 4);
  }
  #pragma unroll
  for (int kg = 0; kg < 4; ++kg)
    #pragma unroll
    for (int n = 0; n < 16; ++n) {
      bf16x8_t b = *(const bf16x8_t*)(Wb2 + (size_t)(kg*24 + n) * 512 + lane * 8);
      acc[n] = __builtin_amdgcn_mfma_f32_16x16x32_bf16(af[kg], b, acc[n], 0,0,0);
    }
  #pragma unroll
  for (int kg = 0; kg < 4; ++kg) af[kg] = pack8(q[2*kg], q[2*kg+1]);
  #pragma unroll
  for (int kg = 4; kg < 8; ++kg)
    #pragma unroll
    for (int n = 0; n < 16; ++n) {
      bf16x8_t b = *(const bf16x8_t*)(Wb2 + (size_t)(kg*24 + n) * 512 + lane * 8);
      acc[n] = __builtin_amdgcn_mfma_f32_16x16x32_bf16(af[kg-4], b, acc[n], 0,0,0);
    }

  // Epilogue: single out write; nb add for cols<128 (wave-local LDS, no barrier)
  const int l15 = lane & 15, lq = lane >> 4;
  const unsigned short* nb16 = (const unsigned short*)nbu;
  #pragma unroll
  for (int n = 0; n < 16; ++n) {
    int col = n * 16 + l15;
    float bias = w0_b[col];
    #pragma unroll
    for (int r = 0; r < 4; ++r) {
      int lrow = lq * 4 + r;
      float v = acc[n][r] + bias;
      if (n < 8) v += bf2f(nb16[(wv * 16 + lrow) * 130 + col]);
      out[(size_t)(rBase + lrow) * 256 + col] = v;
    }
  }
}

// ---------------------------------------------------------------------------
// CSR build
// ---------------------------------------------------------------------------
__global__ void count_deg(const int* __restrict__ edges, int* __restrict__ deg) {
  int i = blockIdx.x * blockDim.x + threadIdx.x;
  if (i >= 2 * E) return;
  int e = i >> 1, half = i & 1;
  atomicAdd(&deg[edges[2 * e + half]], 1);
}

__global__ void scan1(const int* __restrict__ deg, int* __restrict__ rowptr,
                      int* __restrict__ bsums) {
  __shared__ int sm[256];
  int i = blockIdx.x * 256 + threadIdx.x;
  int v = (i < V) ? deg[i] : 0;
  sm[threadIdx.x] = v;
  __syncthreads();
  for (int off = 1; off < 256; off <<= 1) {
    int t = (threadIdx.x >= off) ? sm[threadIdx.x - off] : 0;
    __syncthreads();
    sm[threadIdx.x] += t;
    __syncthreads();
  }
  if (i < V) rowptr[i] = sm[threadIdx.x] - v;
  if (threadIdx.x == 255) bsums[blockIdx.x] = sm[255];
}

__global__ void scan2(int* __restrict__ bsums) {
  __shared__ int sm[1024];
  int t = threadIdx.x;
  int v = (t < NB1) ? bsums[t] : 0;
  sm[t] = v;
  __syncthreads();
  for (int off = 1; off < 1024; off <<= 1) {
    int x = (t >= off) ? sm[t - off] : 0;
    __syncthreads();
    sm[t] += x;
    __syncthreads();
  }
  if (t < NB1) bsums[t] = sm[t] - v;
}

__global__ void scan3(int* __restrict__ rowptr, const int* __restrict__ bsums,
                      int* __restrict__ cursor) {
  int i = blockIdx.x * 256 + threadIdx.x;
  if (i < V) {
    int r = rowptr[i] + bsums[blockIdx.x];
    rowptr[i] = r;
    cursor[i] = r;
  }
  if (i == 0) rowptr[V] = 2 * E;
}

__global__ void fill_adj(const int* __restrict__ edges, int* __restrict__ cursor,
                         int* __restrict__ adj) {
  int i = blockIdx.x * blockDim.x + threadIdx.x;
  if (i >= 2 * E) return;
  int e = i >> 1, half = i & 1;
  int dst = edges[2 * e + half];
  int src = edges[2 * e + (half ^ 1)];
  adj[atomicAdd(&cursor[dst], 1)] = src;
}

// ---------------------------------------------------------------------------
extern "C" void kernel_launch(void* const* d_in, const int* in_sizes, int n_in,
                              void* d_out, int out_size, void* d_ws, size_t ws_size,
                              hipStream_t stream)
{
  const float* verts = (const float*)d_in[0];
  const int*   edges = (const int*)d_in[1];
  const float* w0_w  = (const float*)d_in[2];
  const float* w0_b  = (const float*)d_in[3];
  const float* w1_w  = (const float*)d_in[4];
  const float* w1_b  = (const float*)d_in[5];
  float* out = (float*)d_out;
  char*  ws  = (char*)d_ws;

  // workspace layout (bytes), total ~58.8 MB
  unsigned short* w1b = (unsigned short*)(ws);            // V*128*2 = 51,200,000
  int* rowptr = (int*)(ws + 51200000);                    // (V+1)*4
  int* cursor = (int*)(ws + 52000256);                    // V*4
  int* adj    = (int*)(ws + 52800256);                    // (2E+8)*4
  int* deg    = (int*)(ws + 57600288);                    // V*4
  int* bsums  = (int*)(ws + 58400288);                    // 1024*4
  unsigned short* Wb2 = (unsigned short*)(ws + 58404384); // 98304*2 = 196,608

  hipMemsetAsync(deg, 0, V * sizeof(int), stream);
  hipMemsetAsync(adj + 2 * E, 0, 8 * sizeof(int), stream);   // gather pad

  prep_w2<<<384, 256, 0, stream>>>(w0_w, w1_w, Wb2);

  gemm_w1<<<(V + 63) / 64, 256, 0, stream>>>(verts, Wb2, w1_b, w1b);

  count_deg<<<(2 * E + 255) / 256, 256, 0, stream>>>(edges, deg);
  scan1<<<NB1, 256, 0, stream>>>(deg, rowptr, bsums);
  scan2<<<1, 1024, 0, stream>>>(bsums);
  scan3<<<NB1, 256, 0, stream>>>(rowptr, bsums, cursor);
  fill_adj<<<(2 * E + 255) / 256, 256, 0, stream>>>(edges, cursor, adj);

  gemm_w0_gather<<<(V + 63) / 64, 256, 0, stream>>>(
      verts, Wb2, w0_b, rowptr, adj, w1b, out);
}